// Round 4
// baseline (135.283 us; speedup 1.0000x reference)
//
#include <hip/hip_runtime.h>
#include <hip/hip_bf16.h>

// ContactPredictionHead: logits[b,i,j,o] = sum_d h[b,i,d]*h[b,j,d]*Wp[o,d] + bias[o]
// (diff term is antisymmetric -> cancels under symmetrization; prod term is symmetric.)
// Batched GEMM: per batch  C[2048 x 4096] = A[2048 x 1280] * Beff^T,
//   Beff[2j+o, d] = h[b,j,d] * Wp[o,d],  row-major C == d_out layout.
// Round 4: triangle GEMM (136/256 supertiles per batch) with the mirror fused
// into the epilogue as register-direct global stores: for strict-lower
// supertiles, also emit out[b, j, 2i+o] = C[i, 2j+o] + bias[o]. No LDS reuse,
// no extra barriers -> race-free by construction (disjoint write regions,
// each output element written exactly once per call).

typedef __attribute__((ext_vector_type(8))) short bf16x8;
typedef __attribute__((ext_vector_type(4))) float f32x4;

constexpr int cB = 4, cL = 2048, cD = 1280, cO = 2;
constexpr int BM = 128, BN = 128, BK = 64;
constexpr int KT = cD / BK;            // 20
constexpr int NROW = cL * cO;          // 4096
constexpr int NSUP = 136;              // 16*17/2 lower-tri supertiles per batch
constexpr int NBLK = cB * NSUP * 2;    // 1088 (two 128-col tiles per supertile); %8==0

__device__ __forceinline__ unsigned short f2bf(float f) {
  unsigned int u = __float_as_uint(f);
  u += 0x7fffu + ((u >> 16) & 1u);
  return (unsigned short)(u >> 16);
}

#define GLOAD_LDS16(g, l)                                           \
  __builtin_amdgcn_global_load_lds(                                 \
      (const __attribute__((address_space(1))) void*)(g),           \
      (__attribute__((address_space(3))) void*)(l), 16, 0, 0)

// ---------------- pack: h -> bf16 A, (h*Wp) -> bf16 Beff ----------------
constexpr int ACH = cB * cL * cD / 8;       // 1,310,720 chunks of 8
constexpr int BCH = cB * 2 * cL * cD / 8;   // 2,621,440 chunks of 8

__global__ __launch_bounds__(256) void cph_pack(
    const float* __restrict__ h, const float* __restrict__ W,
    unsigned short* __restrict__ Apk, unsigned short* __restrict__ Bpk) {
  int idx = blockIdx.x * 256 + threadIdx.x;
  if (idx < ACH) {
    const float* src = h + (size_t)idx * 8;
    float4 x0 = *(const float4*)src;
    float4 x1 = *(const float4*)(src + 4);
    bf16x8 v;
    v[0] = (short)f2bf(x0.x); v[1] = (short)f2bf(x0.y);
    v[2] = (short)f2bf(x0.z); v[3] = (short)f2bf(x0.w);
    v[4] = (short)f2bf(x1.x); v[5] = (short)f2bf(x1.y);
    v[6] = (short)f2bf(x1.z); v[7] = (short)f2bf(x1.w);
    *(bf16x8*)(Apk + (size_t)idx * 8) = v;
  } else {
    idx -= ACH;
    if (idx >= BCH) return;
    int c = idx % (cD / 8);                 // 0..159
    int n = (idx / (cD / 8)) % (2 * cL);    // 0..4095
    int b = idx / ((cD / 8) * 2 * cL);      // 0..3
    int j = n >> 1, o = n & 1;
    const float* src = h + ((size_t)b * cL + j) * cD + c * 8;
    const float* ws  = W + (size_t)o * (2 * cD) + c * 8;   // Wp row o
    float4 x0 = *(const float4*)src;
    float4 x1 = *(const float4*)(src + 4);
    float4 w0 = *(const float4*)ws;
    float4 w1 = *(const float4*)(ws + 4);
    bf16x8 v;
    v[0] = (short)f2bf(x0.x * w0.x); v[1] = (short)f2bf(x0.y * w0.y);
    v[2] = (short)f2bf(x0.z * w0.z); v[3] = (short)f2bf(x0.w * w0.w);
    v[4] = (short)f2bf(x1.x * w1.x); v[5] = (short)f2bf(x1.y * w1.y);
    v[6] = (short)f2bf(x1.z * w1.z); v[7] = (short)f2bf(x1.w * w1.w);
    *(bf16x8*)(Bpk + ((size_t)b * (2 * cL) + n) * cD + c * 8) = v;
  }
}

// ---------------- GEMM: 128x128 tile, BK=64, 4 waves (2x2), 16x16x32 bf16 ----------------
// LDS chunk swizzle: logical chunk kc of row r lives at physical chunk kc^(r&7)
// (applied on the global SOURCE address for global_load_lds, and on ds_read).
template <int PACKED>
__global__ __launch_bounds__(256) void cph_gemm(
    const float* __restrict__ h, const float* __restrict__ W,
    const unsigned short* __restrict__ Apk, const unsigned short* __restrict__ Bpk,
    const float* __restrict__ bias, float* __restrict__ out) {
  __shared__ unsigned short Alds[BM][BK];
  __shared__ unsigned short Blds[BN][BK];

  // bijective XCD swizzle (NBLK % 8 == 0)
  int bid = ((int)blockIdx.x & 7) * (NBLK / 8) + ((int)blockIdx.x >> 3);
  int b   = bid / (NSUP * 2);
  int rem = bid % (NSUP * 2);
  int s   = rem >> 1, hh = rem & 1;
  // triangular decode: s -> (a,bb) with a >= bb
  int a = 0;
  while ((a + 1) * (a + 2) / 2 <= s) ++a;
  int bb = s - a * (a + 1) / 2;
  int mt = a;                 // i-tile (128 rows)
  int nt = 2 * bb + hh;       // n-tile (128 cols = 64 j x 2 o)
  bool diag = (a == bb);

  int tid  = threadIdx.x;
  int wave = tid >> 6, lane = tid & 63;
  int wm = wave >> 1, wn = wave & 1;

  f32x4 acc[4][4] = {};

  for (int kt = 0; kt < KT; ++kt) {
    __syncthreads();  // previous tile's ds_reads done before overwrite
    if (PACKED) {
#pragma unroll
      for (int q = 0; q < 4; ++q) {
        int qi  = wave * 4 + q;          // 0..15 instruction slots
        int row = qi * 8 + (lane >> 3);  // lds row this lane's 16B lands in
        int pc  = lane & 7;              // lds physical chunk
        int gc  = pc ^ (row & 7);        // inverse-swizzled global chunk
        const unsigned short* gA =
            Apk + ((size_t)b * cL + mt * BM + row) * cD + kt * BK + gc * 8;
        GLOAD_LDS16(gA, (char*)(&Alds[0][0]) + qi * 1024);
        const unsigned short* gB =
            Bpk + ((size_t)b * NROW + nt * BN + row) * cD + kt * BK + gc * 8;
        GLOAD_LDS16(gB, (char*)(&Blds[0][0]) + qi * 1024);
      }
    } else {
      // fused fallback: fp32 -> bf16 reg-staging (used only if ws too small)
#pragma unroll
      for (int it = 0; it < 4; ++it) {
        int chunk = tid + it * 256;      // 0..1023
        int row = chunk >> 3, c = chunk & 7;
        int pc = c ^ (row & 7);
        const float* asrc = h + ((size_t)b * cL + mt * BM + row) * cD + kt * BK + c * 8;
        float4 a0 = *(const float4*)asrc;
        float4 a1 = *(const float4*)(asrc + 4);
        bf16x8 va;
        va[0] = (short)f2bf(a0.x); va[1] = (short)f2bf(a0.y);
        va[2] = (short)f2bf(a0.z); va[3] = (short)f2bf(a0.w);
        va[4] = (short)f2bf(a1.x); va[5] = (short)f2bf(a1.y);
        va[6] = (short)f2bf(a1.z); va[7] = (short)f2bf(a1.w);
        *(bf16x8*)&Alds[row][pc * 8] = va;

        int n = nt * BN + row;
        int j = n >> 1, o = n & 1;
        const float* bsrc = h + ((size_t)b * cL + j) * cD + kt * BK + c * 8;
        const float* wsrc = W + (size_t)o * (2 * cD) + kt * BK + c * 8;
        float4 b0 = *(const float4*)bsrc;
        float4 b1 = *(const float4*)(bsrc + 4);
        float4 w0 = *(const float4*)wsrc;
        float4 w1 = *(const float4*)(wsrc + 4);
        bf16x8 vb;
        vb[0] = (short)f2bf(b0.x * w0.x); vb[1] = (short)f2bf(b0.y * w0.y);
        vb[2] = (short)f2bf(b0.z * w0.z); vb[3] = (short)f2bf(b0.w * w0.w);
        vb[4] = (short)f2bf(b1.x * w1.x); vb[5] = (short)f2bf(b1.y * w1.y);
        vb[6] = (short)f2bf(b1.z * w1.z); vb[7] = (short)f2bf(b1.w * w1.w);
        *(bf16x8*)&Blds[row][pc * 8] = vb;
      }
    }
    __syncthreads();

#pragma unroll
    for (int kk = 0; kk < 2; ++kk) {
      int kc = kk * 4 + (lane >> 4);   // logical 8-elem chunk within BK
      bf16x8 af[4], bfr[4];
#pragma unroll
      for (int m = 0; m < 4; ++m) {
        int r = wm * 64 + m * 16 + (lane & 15);
        af[m] = *(const bf16x8*)&Alds[r][(kc ^ (r & 7)) * 8];
      }
#pragma unroll
      for (int n = 0; n < 4; ++n) {
        int r = wn * 64 + n * 16 + (lane & 15);
        bfr[n] = *(const bf16x8*)&Blds[r][(kc ^ (r & 7)) * 8];
      }
#pragma unroll
      for (int m = 0; m < 4; ++m)
#pragma unroll
        for (int n = 0; n < 4; ++n)
          acc[m][n] = __builtin_amdgcn_mfma_f32_16x16x32_bf16(af[m], bfr[n], acc[m][n], 0, 0, 0);
    }
  }

  // ---- direct epilogue: C/D layout col = lane&15, row = (lane>>4)*4 + reg ----
  int i0 = mt * BM + wm * 64 + ((lane >> 4) << 2);
  int n0 = nt * BN + wn * 64 + (lane & 15);
  float badd = bias[n0 & 1];  // col parity is lane-invariant across nf (16*nf even)
  float* outb = out + (size_t)b * cL * NROW;
#pragma unroll
  for (int mf = 0; mf < 4; ++mf) {
#pragma unroll
    for (int r = 0; r < 4; ++r) {
      size_t rowoff = (size_t)(i0 + mf * 16 + r) * NROW;
#pragma unroll
      for (int nf = 0; nf < 4; ++nf)
        outb[rowoff + n0 + nf * 16] = acc[mf][nf][r] + badd;
    }
  }

  // ---- fused mirror (strict-lower supertiles): out[b, j, 2i+o] = C[i, n] + bias[o]
  // j = n>>1, o = n&1. Register-direct stores; adjacent even/odd lanes emit
  // adjacent 4B -> 8B chunks, r-loop fills 32B runs; L2 combines into full lines.
  if (!diag) {
    int j0 = n0 >> 1;                    // base mirror row (nf advances by 8)
    size_t colb = 2 * (size_t)i0 + (size_t)(n0 & 1);
#pragma unroll
    for (int nf = 0; nf < 4; ++nf) {
      size_t rowoff = (size_t)(j0 + 8 * nf) * NROW;
#pragma unroll
      for (int mf = 0; mf < 4; ++mf) {
#pragma unroll
        for (int r = 0; r < 4; ++r)
          outb[rowoff + colb + 32 * mf + 2 * r] = acc[mf][nf][r] + badd;
      }
    }
  }
}

extern "C" void kernel_launch(void* const* d_in, const int* in_sizes, int n_in,
                              void* d_out, int out_size, void* d_ws, size_t ws_size,
                              hipStream_t stream) {
  const float* h    = (const float*)d_in[0];
  const float* W    = (const float*)d_in[1];
  const float* bias = (const float*)d_in[2];
  float* out        = (float*)d_out;

  size_t a_elems = (size_t)cB * cL * cD;          // 10.49M
  size_t b_elems = (size_t)cB * 2 * cL * cD;      // 20.97M
  size_t need = (a_elems + b_elems) * sizeof(unsigned short);  // ~63 MB

  if (ws_size >= need) {
    unsigned short* Apk = (unsigned short*)d_ws;
    unsigned short* Bpk = Apk + a_elems;
    int total_chunks = ACH + BCH;
    cph_pack<<<(total_chunks + 255) / 256, 256, 0, stream>>>(h, W, Apk, Bpk);
    cph_gemm<1><<<NBLK, 256, 0, stream>>>(h, W, Apk, Bpk, bias, out);
  } else {
    cph_gemm<0><<<NBLK, 256, 0, stream>>>(h, W, nullptr, nullptr, bias, out);
  }
}

// Round 5
// 115.916 us; speedup vs baseline: 1.1671x; 1.1671x over previous
//
#include <hip/hip_runtime.h>
#include <hip/hip_bf16.h>

// ContactPredictionHead: logits[b,i,j,o] = sum_d h[b,i,d]*h[b,j,d]*Wp[o,d] + bias[o]
// (diff term is antisymmetric -> cancels under symmetrization; prod term is symmetric.)
// Batched GEMM: per batch  C[2048 x 4096] = A[2048 x 1280] * Beff^T,
//   Beff[2j+o, d] = h[b,j,d] * Wp[o,d],  row-major C == d_out layout.
// Round 5: full grid (symmetry tricks measured a wash in rounds 3/4), but the
// GEMM moves to the 256x256 8-wave counted-vmcnt structure (T2+T3+T4+T5):
//   - 2x double-buffered 64KB K-tile buffers (128 KB LDS), global_load_lds
//     staging with pre-swizzled source (XOR chunk^(row&7), both-sides).
//   - per K-tile: compute(64 MFMA/wave) -> barrier -> stage(t+2) -> vmcnt(8)
//     -> barrier. Loads for tile t+2 stay in flight across tile t+1's compute.
//   - raw asm s_barrier with "memory" clobber (no compiler vmcnt(0) drain).

typedef __attribute__((ext_vector_type(8))) short bf16x8;
typedef __attribute__((ext_vector_type(4))) float f32x4;

constexpr int cB = 4, cL = 2048, cD = 1280, cO = 2;
constexpr int NROW = cL * cO;          // 4096
constexpr int BM = 256, BN = 256, BK = 64;
constexpr int KT = cD / BK;            // 20
constexpr int MT2 = cL / BM;           // 8
constexpr int NT2 = NROW / BN;         // 16
constexpr int NBLK2 = cB * MT2 * NT2;  // 512  (%8==0 -> bijective XCD swizzle)

__device__ __forceinline__ unsigned short f2bf(float f) {
  unsigned int u = __float_as_uint(f);
  u += 0x7fffu + ((u >> 16) & 1u);
  return (unsigned short)(u >> 16);
}

#define GLOAD_LDS16(g, l)                                           \
  __builtin_amdgcn_global_load_lds(                                 \
      (const __attribute__((address_space(1))) void*)(g),           \
      (__attribute__((address_space(3))) void*)(l), 16, 0, 0)

// ---------------- pack: h -> bf16 A, (h*Wp) -> bf16 Beff ----------------
constexpr int ACH = cB * cL * cD / 8;       // 1,310,720 chunks of 8
constexpr int BCH = cB * 2 * cL * cD / 8;   // 2,621,440 chunks of 8

__global__ __launch_bounds__(256) void cph_pack(
    const float* __restrict__ h, const float* __restrict__ W,
    unsigned short* __restrict__ Apk, unsigned short* __restrict__ Bpk) {
  int idx = blockIdx.x * 256 + threadIdx.x;
  if (idx < ACH) {
    const float* src = h + (size_t)idx * 8;
    float4 x0 = *(const float4*)src;
    float4 x1 = *(const float4*)(src + 4);
    bf16x8 v;
    v[0] = (short)f2bf(x0.x); v[1] = (short)f2bf(x0.y);
    v[2] = (short)f2bf(x0.z); v[3] = (short)f2bf(x0.w);
    v[4] = (short)f2bf(x1.x); v[5] = (short)f2bf(x1.y);
    v[6] = (short)f2bf(x1.z); v[7] = (short)f2bf(x1.w);
    *(bf16x8*)(Apk + (size_t)idx * 8) = v;
  } else {
    idx -= ACH;
    if (idx >= BCH) return;
    int c = idx % (cD / 8);                 // 0..159
    int n = (idx / (cD / 8)) % (2 * cL);    // 0..4095
    int b = idx / ((cD / 8) * 2 * cL);      // 0..3
    int j = n >> 1, o = n & 1;
    const float* src = h + ((size_t)b * cL + j) * cD + c * 8;
    const float* ws  = W + (size_t)o * (2 * cD) + c * 8;   // Wp row o
    float4 x0 = *(const float4*)src;
    float4 x1 = *(const float4*)(src + 4);
    float4 w0 = *(const float4*)ws;
    float4 w1 = *(const float4*)(ws + 4);
    bf16x8 v;
    v[0] = (short)f2bf(x0.x * w0.x); v[1] = (short)f2bf(x0.y * w0.y);
    v[2] = (short)f2bf(x0.z * w0.z); v[3] = (short)f2bf(x0.w * w0.w);
    v[4] = (short)f2bf(x1.x * w1.x); v[5] = (short)f2bf(x1.y * w1.y);
    v[6] = (short)f2bf(x1.z * w1.z); v[7] = (short)f2bf(x1.w * w1.w);
    *(bf16x8*)(Bpk + ((size_t)b * (2 * cL) + n) * cD + c * 8) = v;
  }
}

// ------------- GEMM: 256x256 tile, BK=64, 8 waves (2M x 4N), dbuf + counted vmcnt -------------
__global__ __launch_bounds__(512, 2) void cph_gemm256(
    const unsigned short* __restrict__ Apk, const unsigned short* __restrict__ Bpk,
    const float* __restrict__ bias, float* __restrict__ out) {
  __shared__ __align__(16) char smem[131072];  // [2 buf][A 32K | B 32K]

  // bijective XCD swizzle
  int bid = ((int)blockIdx.x & 7) * (NBLK2 / 8) + ((int)blockIdx.x >> 3);
  int b   = bid / (MT2 * NT2);
  int rem = bid % (MT2 * NT2);
  int mt  = rem / NT2, nt = rem % NT2;

  int tid  = threadIdx.x;
  int wave = tid >> 6, lane = tid & 63;
  int wm = wave >> 2, wn = wave & 3;   // 2 x 4 wave grid; per-wave C = 128 x 64

  const unsigned short* Ab = Apk + ((size_t)b * cL + mt * BM) * cD;
  const unsigned short* Bb = Bpk + ((size_t)b * NROW + nt * BN) * cD;

  // staging: 4 A-insts + 4 B-insts per thread per K-tile (16B each).
  // LDS slot (q*8+wave) covers rows [(q*8+wave)*8, +8); lane row = +(lane>>3),
  // chunk pc = lane&7 holds global chunk gc = pc ^ (row&7)  (row&7 == lane>>3).
  int srow = wave * 8 + (lane >> 3);
  int gc8  = ((lane & 7) ^ (lane >> 3)) * 8;
#define STAGE(kt, bufsel)                                                     \
  {                                                                           \
    char* Al_ = smem + (bufsel) * 65536;                                      \
    char* Bl_ = smem + (bufsel) * 65536 + 32768;                              \
    _Pragma("unroll")                                                         \
    for (int q = 0; q < 4; ++q) {                                             \
      int row = q * 64 + srow;                                                \
      GLOAD_LDS16(Ab + (size_t)row * cD + (kt) * BK + gc8,                    \
                  Al_ + (q * 8 + wave) * 1024);                               \
      GLOAD_LDS16(Bb + (size_t)row * cD + (kt) * BK + gc8,                    \
                  Bl_ + (q * 8 + wave) * 1024);                               \
    }                                                                         \
  }

  f32x4 acc[8][4] = {};

  STAGE(0, 0);
  STAGE(1, 1);
  asm volatile("s_waitcnt vmcnt(8)" ::: "memory");   // tile 0 complete
  asm volatile("s_barrier" ::: "memory");

  for (int t = 0; t < KT; ++t) {
    int cur = t & 1;
    const unsigned short* Al = (const unsigned short*)(smem + cur * 65536);
    const unsigned short* Bl = (const unsigned short*)(smem + cur * 65536 + 32768);
#pragma unroll
    for (int kk = 0; kk < 2; ++kk) {
      int kc = kk * 4 + (lane >> 4);   // logical 16B chunk within BK
      bf16x8 bfr[4];
#pragma unroll
      for (int nf = 0; nf < 4; ++nf) {
        int r = wn * 64 + nf * 16 + (lane & 15);
        bfr[nf] = *(const bf16x8*)(Bl + (size_t)r * 64 + (size_t)((kc ^ (r & 7)) * 8));
      }
      bf16x8 af[8];
#pragma unroll
      for (int mf = 0; mf < 8; ++mf) {
        int r = wm * 128 + mf * 16 + (lane & 15);
        af[mf] = *(const bf16x8*)(Al + (size_t)r * 64 + (size_t)((kc ^ (r & 7)) * 8));
      }
      __builtin_amdgcn_s_setprio(1);
#pragma unroll
      for (int mf = 0; mf < 8; ++mf)
#pragma unroll
        for (int nf = 0; nf < 4; ++nf)
          acc[mf][nf] = __builtin_amdgcn_mfma_f32_16x16x32_bf16(af[mf], bfr[nf], acc[mf][nf], 0, 0, 0);
      __builtin_amdgcn_s_setprio(0);
    }
    asm volatile("s_barrier" ::: "memory");          // all waves done reading buf[cur]
    if (t + 2 < KT) {
      STAGE(t + 2, cur);                             // refill freed buffer
      asm volatile("s_waitcnt vmcnt(8)" ::: "memory");  // tile t+1 done; t+2 in flight
      asm volatile("s_barrier" ::: "memory");
    } else if (t + 1 < KT) {
      asm volatile("s_waitcnt vmcnt(0)" ::: "memory");  // drain tile t+1 (tail)
      asm volatile("s_barrier" ::: "memory");
    }
  }

  // epilogue: C/D 16x16 layout col = lane&15, row = (lane>>4)*4 + reg
  int i0 = mt * BM + wm * 128 + ((lane >> 4) << 2);
  int n0 = nt * BN + wn * 64 + (lane & 15);
  float badd = bias[n0 & 1];   // col parity lane-invariant across nf (16*nf even)
  float* outb = out + (size_t)b * cL * NROW;
#pragma unroll
  for (int mf = 0; mf < 8; ++mf) {
#pragma unroll
    for (int r = 0; r < 4; ++r) {
      size_t rowoff = (size_t)(i0 + mf * 16 + r) * NROW;
#pragma unroll
      for (int nf = 0; nf < 4; ++nf)
        outb[rowoff + n0 + nf * 16] = acc[mf][nf][r] + badd;
    }
  }
#undef STAGE
}

// ---------------- fallback (ws too small): fused 128^2 full-grid GEMM ----------------
constexpr int fBM = 128, fBK = 64;
constexpr int fMT = cL / fBM, fNT = NROW / fBM;       // 16, 32
constexpr int fNBLK = cB * fMT * fNT;                 // 2048

__global__ __launch_bounds__(256) void cph_gemm_fb(
    const float* __restrict__ h, const float* __restrict__ W,
    const float* __restrict__ bias, float* __restrict__ out) {
  __shared__ unsigned short Alds[fBM][fBK];
  __shared__ unsigned short Blds[fBM][fBK];
  int bid = ((int)blockIdx.x & 7) * (fNBLK / 8) + ((int)blockIdx.x >> 3);
  int b   = bid / (fMT * fNT);
  int rem = bid % (fMT * fNT);
  int mt  = rem / fNT, nt = rem % fNT;
  int tid = threadIdx.x, wave = tid >> 6, lane = tid & 63;
  int wm = wave >> 1, wn = wave & 1;
  f32x4 acc[4][4] = {};
  for (int kt = 0; kt < KT; ++kt) {
    __syncthreads();
#pragma unroll
    for (int it = 0; it < 4; ++it) {
      int chunk = tid + it * 256;
      int row = chunk >> 3, c = chunk & 7;
      int pc = c ^ (row & 7);
      const float* asrc = h + ((size_t)b * cL + mt * fBM + row) * cD + kt * fBK + c * 8;
      float4 a0 = *(const float4*)asrc;
      float4 a1 = *(const float4*)(asrc + 4);
      bf16x8 va;
      va[0] = (short)f2bf(a0.x); va[1] = (short)f2bf(a0.y);
      va[2] = (short)f2bf(a0.z); va[3] = (short)f2bf(a0.w);
      va[4] = (short)f2bf(a1.x); va[5] = (short)f2bf(a1.y);
      va[6] = (short)f2bf(a1.z); va[7] = (short)f2bf(a1.w);
      *(bf16x8*)&Alds[row][pc * 8] = va;
      int n = nt * fBM + row;
      int j = n >> 1, o = n & 1;
      const float* bsrc = h + ((size_t)b * cL + j) * cD + kt * fBK + c * 8;
      const float* wsrc = W + (size_t)o * (2 * cD) + kt * fBK + c * 8;
      float4 b0 = *(const float4*)bsrc;
      float4 b1 = *(const float4*)(bsrc + 4);
      float4 w0 = *(const float4*)wsrc;
      float4 w1 = *(const float4*)(wsrc + 4);
      bf16x8 vb;
      vb[0] = (short)f2bf(b0.x * w0.x); vb[1] = (short)f2bf(b0.y * w0.y);
      vb[2] = (short)f2bf(b0.z * w0.z); vb[3] = (short)f2bf(b0.w * w0.w);
      vb[4] = (short)f2bf(b1.x * w1.x); vb[5] = (short)f2bf(b1.y * w1.y);
      vb[6] = (short)f2bf(b1.z * w1.z); vb[7] = (short)f2bf(b1.w * w1.w);
      *(bf16x8*)&Blds[row][pc * 8] = vb;
    }
    __syncthreads();
#pragma unroll
    for (int kk = 0; kk < 2; ++kk) {
      int kc = kk * 4 + (lane >> 4);
      bf16x8 af[4], bfr[4];
#pragma unroll
      for (int m = 0; m < 4; ++m) {
        int r = wm * 64 + m * 16 + (lane & 15);
        af[m] = *(const bf16x8*)&Alds[r][(kc ^ (r & 7)) * 8];
      }
#pragma unroll
      for (int n = 0; n < 4; ++n) {
        int r = wn * 64 + n * 16 + (lane & 15);
        bfr[n] = *(const bf16x8*)&Blds[r][(kc ^ (r & 7)) * 8];
      }
#pragma unroll
      for (int m = 0; m < 4; ++m)
#pragma unroll
        for (int n = 0; n < 4; ++n)
          acc[m][n] = __builtin_amdgcn_mfma_f32_16x16x32_bf16(af[m], bfr[n], acc[m][n], 0, 0, 0);
    }
  }
  int i0 = mt * fBM + wm * 64 + ((lane >> 4) << 2);
  int n0 = nt * fBM + wn * 64 + (lane & 15);
  float badd = bias[n0 & 1];
  float* outb = out + (size_t)b * cL * NROW;
#pragma unroll
  for (int mf = 0; mf < 4; ++mf)
#pragma unroll
    for (int r = 0; r < 4; ++r) {
      size_t rowoff = (size_t)(i0 + mf * 16 + r) * NROW;
#pragma unroll
      for (int nf = 0; nf < 4; ++nf)
        outb[rowoff + n0 + nf * 16] = acc[mf][nf][r] + badd;
    }
}

extern "C" void kernel_launch(void* const* d_in, const int* in_sizes, int n_in,
                              void* d_out, int out_size, void* d_ws, size_t ws_size,
                              hipStream_t stream) {
  const float* h    = (const float*)d_in[0];
  const float* W    = (const float*)d_in[1];
  const float* bias = (const float*)d_in[2];
  float* out        = (float*)d_out;

  size_t a_elems = (size_t)cB * cL * cD;          // 10.49M
  size_t b_elems = (size_t)cB * 2 * cL * cD;      // 20.97M
  size_t need = (a_elems + b_elems) * sizeof(unsigned short);  // ~63 MB

  if (ws_size >= need) {
    unsigned short* Apk = (unsigned short*)d_ws;
    unsigned short* Bpk = Apk + a_elems;
    int total_chunks = ACH + BCH;
    cph_pack<<<(total_chunks + 255) / 256, 256, 0, stream>>>(h, W, Apk, Bpk);
    cph_gemm256<<<NBLK2, 512, 0, stream>>>(Apk, Bpk, bias, out);
  } else {
    cph_gemm_fb<<<fNBLK, 256, 0, stream>>>(h, W, bias, out);
  }
}

// Round 6
// 114.739 us; speedup vs baseline: 1.1790x; 1.0103x over previous
//
#include <hip/hip_runtime.h>
#include <hip/hip_bf16.h>

// ContactPredictionHead: logits[b,i,j,o] = sum_d h[b,i,d]*h[b,j,d]*Wp[o,d] + bias[o]
// (diff term antisymmetric -> cancels under symmetrization; prod term symmetric.)
// Batched GEMM: per batch  C[2048 x 4096] = A[2048 x 1280] * Beff^T,
//   Beff[2j+o, d] = h[b,j,d] * Wp[o,d],  row-major C == d_out layout.
// Round 6: 256x256 8-wave GEMM with the 8-phase (4 phases/K-tile) fine
// interleave + counted vmcnt(6) (T2+T3+T4+T5). Stage/read safety proof:
//   reads of buf X, tile t:  B(X) at phase (t,0) only; A(X) quarter q at (t,q).
//   stages (2 gloads/phase): (t,0): A(X^1,t+1) stripes 2,3   [freed (t-1,2/3)]
//                            (t,1): B(X,t+2) half0           [freed (t,0)]
//                            (t,2): B(X,t+2) half1           [freed (t,0)]
//                            (t,3): A(X,t+2) stripes 0,1     [freed (t,0/1)]
//   every stage issues >=1 closing-barrier after the region's last ds_read
//   (lgkmcnt(0) precedes each MFMA, so reads are complete at that barrier).
//   vmcnt(6) before each tile-closing barrier => next tile's 8 loads landed.

typedef __attribute__((ext_vector_type(8))) short bf16x8;
typedef __attribute__((ext_vector_type(4))) float f32x4;

constexpr int cB = 4, cL = 2048, cD = 1280, cO = 2;
constexpr int NROW = cL * cO;          // 4096
constexpr int BM = 256, BN = 256, BK = 64;
constexpr int KT = cD / BK;            // 20 (even)
constexpr int MT2 = cL / BM;           // 8
constexpr int NT2 = NROW / BN;         // 16
constexpr int NBLK2 = cB * MT2 * NT2;  // 512

__device__ __forceinline__ unsigned short f2bf(float f) {
  unsigned int u = __float_as_uint(f);
  u += 0x7fffu + ((u >> 16) & 1u);
  return (unsigned short)(u >> 16);
}

#define GLOAD_LDS16(g, l)                                           \
  __builtin_amdgcn_global_load_lds(                                 \
      (const __attribute__((address_space(1))) void*)(g),           \
      (__attribute__((address_space(3))) void*)(l), 16, 0, 0)

// ---------------- pack: h -> bf16 A, (h*Wp) -> bf16 Beff ----------------
constexpr int ACH = cB * cL * cD / 8;
constexpr int BCH = cB * 2 * cL * cD / 8;

__global__ __launch_bounds__(256) void cph_pack(
    const float* __restrict__ h, const float* __restrict__ W,
    unsigned short* __restrict__ Apk, unsigned short* __restrict__ Bpk) {
  int idx = blockIdx.x * 256 + threadIdx.x;
  if (idx < ACH) {
    const float* src = h + (size_t)idx * 8;
    float4 x0 = *(const float4*)src;
    float4 x1 = *(const float4*)(src + 4);
    bf16x8 v;
    v[0] = (short)f2bf(x0.x); v[1] = (short)f2bf(x0.y);
    v[2] = (short)f2bf(x0.z); v[3] = (short)f2bf(x0.w);
    v[4] = (short)f2bf(x1.x); v[5] = (short)f2bf(x1.y);
    v[6] = (short)f2bf(x1.z); v[7] = (short)f2bf(x1.w);
    *(bf16x8*)(Apk + (size_t)idx * 8) = v;
  } else {
    idx -= ACH;
    if (idx >= BCH) return;
    int c = idx % (cD / 8);
    int n = (idx / (cD / 8)) % (2 * cL);
    int b = idx / ((cD / 8) * 2 * cL);
    int j = n >> 1, o = n & 1;
    const float* src = h + ((size_t)b * cL + j) * cD + c * 8;
    const float* ws  = W + (size_t)o * (2 * cD) + c * 8;
    float4 x0 = *(const float4*)src;
    float4 x1 = *(const float4*)(src + 4);
    float4 w0 = *(const float4*)ws;
    float4 w1 = *(const float4*)(ws + 4);
    bf16x8 v;
    v[0] = (short)f2bf(x0.x * w0.x); v[1] = (short)f2bf(x0.y * w0.y);
    v[2] = (short)f2bf(x0.z * w0.z); v[3] = (short)f2bf(x0.w * w0.w);
    v[4] = (short)f2bf(x1.x * w1.x); v[5] = (short)f2bf(x1.y * w1.y);
    v[6] = (short)f2bf(x1.z * w1.z); v[7] = (short)f2bf(x1.w * w1.w);
    *(bf16x8*)(Bpk + ((size_t)b * (2 * cL) + n) * cD + c * 8) = v;
  }
}

// ------------- GEMM: 256x256, 8 waves (2M x 4N), 4-phase/K-tile, vmcnt(6) -------------
__global__ __launch_bounds__(512, 2) void cph_gemm256(
    const unsigned short* __restrict__ Apk, const unsigned short* __restrict__ Bpk,
    const float* __restrict__ bias, float* __restrict__ out) {
  __shared__ __align__(16) char smem[131072];  // [2 buf][A 32K | B 32K]

  int bid = ((int)blockIdx.x & 7) * (NBLK2 / 8) + ((int)blockIdx.x >> 3);
  int b   = bid / (MT2 * NT2);
  int rem = bid % (MT2 * NT2);
  int mt  = rem / NT2, nt = rem % NT2;

  int tid  = threadIdx.x;
  int wave = tid >> 6, lane = tid & 63;
  int wm = wave >> 2, wn = wave & 3;   // per-wave C = 128 x 64

  const unsigned short* Ab = Apk + ((size_t)b * cL + mt * BM) * cD;
  const unsigned short* Bb = Bpk + ((size_t)b * NROW + nt * BN) * cD;

  int lr  = lane >> 3;                  // row within an 8-row slab
  int gc8 = ((lane & 7) ^ lr) * 8;      // inverse-swizzled global chunk offset

  // stage one 8-row A slab per wave (1 gload/thread): stripe s = block rows
  // [s*32,+32) u [128+s*32,+32); wave<4 -> piece1, wave>=4 -> piece2.
  auto stageA = [&](int buf, int kt, int s) {
    int r0 = ((wave & 4) << 5) + s * 32 + (wave & 3) * 8;
    GLOAD_LDS16(Ab + (size_t)(r0 + lr) * cD + kt * BK + gc8,
                smem + buf * 65536 + r0 * 128);
  };
  // stage one 16-row B slab per wave (2 gloads/thread): half h = rows [h*128,+128)
  auto stageB = [&](int buf, int kt, int h) {
    int r0 = h * 128 + wave * 16;
    GLOAD_LDS16(Bb + (size_t)(r0 + lr) * cD + kt * BK + gc8,
                smem + buf * 65536 + 32768 + r0 * 128);
    GLOAD_LDS16(Bb + (size_t)(r0 + 8 + lr) * cD + kt * BK + gc8,
                smem + buf * 65536 + 32768 + (r0 + 8) * 128);
  };
  auto ldA = [&](int buf, int m, int kk) -> bf16x8 {
    int r  = wm * 128 + m * 16 + (lane & 15);
    int kc = kk * 4 + (lane >> 4);
    return *(const bf16x8*)(smem + buf * 65536 + r * 128 + (kc ^ (r & 7)) * 16);
  };
  auto ldB = [&](int buf, int nf, int kk) -> bf16x8 {
    int r  = wn * 64 + nf * 16 + (lane & 15);
    int kc = kk * 4 + (lane >> 4);
    return *(const bf16x8*)(smem + buf * 65536 + 32768 + r * 128 + (kc ^ (r & 7)) * 16);
  };

  f32x4 acc[8][4] = {};

  // prologue: tile0 complete (8 loads), tile1 partial (6 loads: B + A stripes 0,1)
  stageB(0, 0, 0); stageB(0, 0, 1);
  stageA(0, 0, 0); stageA(0, 0, 1); stageA(0, 0, 2); stageA(0, 0, 3);
  stageB(1, 1, 0); stageB(1, 1, 1);
  stageA(1, 1, 0); stageA(1, 1, 1);
  asm volatile("s_waitcnt vmcnt(6)" ::: "memory");   // tile 0 landed
  asm volatile("s_barrier" ::: "memory");

  for (int tt = 0; tt < KT; tt += 2) {
    bool more = (tt + 2 < KT);
#pragma unroll
    for (int half = 0; half < 2; ++half) {   // tile t = tt+half in buf X = half
      int t = tt + half;
      const int X = half;
      bf16x8 bfr[4][2];
#pragma unroll
      for (int q = 0; q < 4; ++q) {
        // --- ds_read this phase's operands ---
        bf16x8 af[2][2];
#pragma unroll
        for (int mm = 0; mm < 2; ++mm)
#pragma unroll
          for (int kk = 0; kk < 2; ++kk)
            af[mm][kk] = ldA(X, 2 * q + mm, kk);
        if (q == 0) {
#pragma unroll
          for (int nf = 0; nf < 4; ++nf)
#pragma unroll
            for (int kk = 0; kk < 2; ++kk)
              bfr[nf][kk] = ldB(X, nf, kk);
        }
        // --- stage (2 gloads/thread/phase; regions freed per header proof) ---
        if (q == 0) {
          if (half == 0 || more) { stageA(X ^ 1, t + 1, 2); stageA(X ^ 1, t + 1, 3); }
        } else if (q == 1) {
          if (more) stageB(X, t + 2, 0);
        } else if (q == 2) {
          if (more) stageB(X, t + 2, 1);
        } else {
          if (more) { stageA(X, t + 2, 0); stageA(X, t + 2, 1); }
        }
        asm volatile("s_barrier" ::: "memory");
        // compiler emits lgkmcnt for the af/bfr dependencies
        __builtin_amdgcn_s_setprio(1);
#pragma unroll
        for (int kk = 0; kk < 2; ++kk)
#pragma unroll
          for (int mm = 0; mm < 2; ++mm)
#pragma unroll
            for (int nf = 0; nf < 4; ++nf)
              acc[2 * q + mm][nf] = __builtin_amdgcn_mfma_f32_16x16x32_bf16(
                  af[mm][kk], bfr[nf][kk], acc[2 * q + mm][nf], 0, 0, 0);
        __builtin_amdgcn_s_setprio(0);
        if (q == 3) {
          if (more) asm volatile("s_waitcnt vmcnt(6)" ::: "memory");
          else      asm volatile("s_waitcnt vmcnt(0)" ::: "memory");
        }
        asm volatile("s_barrier" ::: "memory");
      }
    }
  }

  // epilogue: C/D 16x16 layout col = lane&15, row = (lane>>4)*4 + reg
  int i0 = mt * BM + wm * 128 + ((lane >> 4) << 2);
  int n0 = nt * BN + wn * 64 + (lane & 15);
  float badd = bias[n0 & 1];
  float* outb = out + (size_t)b * cL * NROW;
#pragma unroll
  for (int mf = 0; mf < 8; ++mf) {
#pragma unroll
    for (int r = 0; r < 4; ++r) {
      size_t rowoff = (size_t)(i0 + mf * 16 + r) * NROW;
#pragma unroll
      for (int nf = 0; nf < 4; ++nf)
        outb[rowoff + n0 + nf * 16] = acc[mf][nf][r] + badd;
    }
  }
}

// ---------------- fallback (ws too small): fused 128^2 full-grid GEMM ----------------
constexpr int fBM = 128, fBK = 64;
constexpr int fMT = cL / fBM, fNT = NROW / fBM;
constexpr int fNBLK = cB * fMT * fNT;

__global__ __launch_bounds__(256) void cph_gemm_fb(
    const float* __restrict__ h, const float* __restrict__ W,
    const float* __restrict__ bias, float* __restrict__ out) {
  __shared__ unsigned short Alds[fBM][fBK];
  __shared__ unsigned short Blds[fBM][fBK];
  int bid = ((int)blockIdx.x & 7) * (fNBLK / 8) + ((int)blockIdx.x >> 3);
  int b   = bid / (fMT * fNT);
  int rem = bid % (fMT * fNT);
  int mt  = rem / fNT, nt = rem % fNT;
  int tid = threadIdx.x, wave = tid >> 6, lane = tid & 63;
  int wm = wave >> 1, wn = wave & 1;
  f32x4 acc[4][4] = {};
  for (int kt = 0; kt < KT; ++kt) {
    __syncthreads();
#pragma unroll
    for (int it = 0; it < 4; ++it) {
      int chunk = tid + it * 256;
      int row = chunk >> 3, c = chunk & 7;
      int pc = c ^ (row & 7);
      const float* asrc = h + ((size_t)b * cL + mt * fBM + row) * cD + kt * fBK + c * 8;
      float4 a0 = *(const float4*)asrc;
      float4 a1 = *(const float4*)(asrc + 4);
      bf16x8 va;
      va[0] = (short)f2bf(a0.x); va[1] = (short)f2bf(a0.y);
      va[2] = (short)f2bf(a0.z); va[3] = (short)f2bf(a0.w);
      va[4] = (short)f2bf(a1.x); va[5] = (short)f2bf(a1.y);
      va[6] = (short)f2bf(a1.z); va[7] = (short)f2bf(a1.w);
      *(bf16x8*)&Alds[row][pc * 8] = va;
      int n = nt * fBM + row;
      int j = n >> 1, o = n & 1;
      const float* bsrc = h + ((size_t)b * cL + j) * cD + kt * fBK + c * 8;
      const float* wsrc = W + (size_t)o * (2 * cD) + kt * fBK + c * 8;
      float4 b0 = *(const float4*)bsrc;
      float4 b1 = *(const float4*)(bsrc + 4);
      float4 w0 = *(const float4*)wsrc;
      float4 w1 = *(const float4*)(wsrc + 4);
      bf16x8 vb;
      vb[0] = (short)f2bf(b0.x * w0.x); vb[1] = (short)f2bf(b0.y * w0.y);
      vb[2] = (short)f2bf(b0.z * w0.z); vb[3] = (short)f2bf(b0.w * w0.w);
      vb[4] = (short)f2bf(b1.x * w1.x); vb[5] = (short)f2bf(b1.y * w1.y);
      vb[6] = (short)f2bf(b1.z * w1.z); vb[7] = (short)f2bf(b1.w * w1.w);
      *(bf16x8*)&Blds[row][pc * 8] = vb;
    }
    __syncthreads();
#pragma unroll
    for (int kk = 0; kk < 2; ++kk) {
      int kc = kk * 4 + (lane >> 4);
      bf16x8 af[4], bfr[4];
#pragma unroll
      for (int m = 0; m < 4; ++m) {
        int r = wm * 64 + m * 16 + (lane & 15);
        af[m] = *(const bf16x8*)&Alds[r][(kc ^ (r & 7)) * 8];
      }
#pragma unroll
      for (int n = 0; n < 4; ++n) {
        int r = wn * 64 + n * 16 + (lane & 15);
        bfr[n] = *(const bf16x8*)&Blds[r][(kc ^ (r & 7)) * 8];
      }
#pragma unroll
      for (int m = 0; m < 4; ++m)
#pragma unroll
        for (int n = 0; n < 4; ++n)
          acc[m][n] = __builtin_amdgcn_mfma_f32_16x16x32_bf16(af[m], bfr[n], acc[m][n], 0, 0, 0);
    }
  }
  int i0 = mt * fBM + wm * 64 + ((lane >> 4) << 2);
  int n0 = nt * fBM + wn * 64 + (lane & 15);
  float badd = bias[n0 & 1];
  float* outb = out + (size_t)b * cL * NROW;
#pragma unroll
  for (int mf = 0; mf < 4; ++mf)
#pragma unroll
    for (int r = 0; r < 4; ++r) {
      size_t rowoff = (size_t)(i0 + mf * 16 + r) * NROW;
#pragma unroll
      for (int nf = 0; nf < 4; ++nf)
        outb[rowoff + n0 + nf * 16] = acc[mf][nf][r] + badd;
    }
}

extern "C" void kernel_launch(void* const* d_in, const int* in_sizes, int n_in,
                              void* d_out, int out_size, void* d_ws, size_t ws_size,
                              hipStream_t stream) {
  const float* h    = (const float*)d_in[0];
  const float* W    = (const float*)d_in[1];
  const float* bias = (const float*)d_in[2];
  float* out        = (float*)d_out;

  size_t a_elems = (size_t)cB * cL * cD;
  size_t b_elems = (size_t)cB * 2 * cL * cD;
  size_t need = (a_elems + b_elems) * sizeof(unsigned short);

  if (ws_size >= need) {
    unsigned short* Apk = (unsigned short*)d_ws;
    unsigned short* Bpk = Apk + a_elems;
    int total_chunks = ACH + BCH;
    cph_pack<<<(total_chunks + 255) / 256, 256, 0, stream>>>(h, W, Apk, Bpk);
    cph_gemm256<<<NBLK2, 512, 0, stream>>>(Apk, Bpk, bias, out);
  } else {
    cph_gemm_fb<<<fNBLK, 256, 0, stream>>>(h, W, bias, out);
  }
}

// Round 7
// 113.494 us; speedup vs baseline: 1.1920x; 1.0110x over previous
//
#include <hip/hip_runtime.h>
#include <hip/hip_bf16.h>

// ContactPredictionHead: logits[b,i,j,o] = sum_d h[b,i,d]*h[b,j,d]*Wp[o,d] + bias[o]
// (diff term antisymmetric -> cancels under symmetrization; prod term symmetric.)
// Batched GEMM: per batch  C[2048 x 4096] = A[2048 x 1280] * Beff^T,
//   Beff[2j+o, d] = h[b,j,d] * Wp[o,d],  row-major C == d_out layout.
// Round 7: identical 4-phase/K-tile schedule to round 6, but sync idioms ported
// to the verified m201 set: __builtin_amdgcn_s_barrier() (NO implied waitcnt
// drain), waitcnt asm WITHOUT "memory" clobber (a "memory" clobber makes LLVM
// emit a full vmcnt(0) lgkmcnt(0) drain before the asm -- that drain was the
// rounds-5/6 stall), explicit lgkmcnt(0)+sched_barrier(0) before each MFMA
// cluster (rule 18). Stage/read safety proof unchanged:
//   reads of buf X, tile t:  B(X) at phase (t,0) only; A(X) quarter q at (t,q).
//   stages: (t,0): A(X^1,t+1) str 2,3 | (t,1): B(X,t+2) h0 | (t,2): B(X,t+2) h1
//           (t,3): A(X,t+2) str 0,1  -- every staged region's last ds_read
//   completed (lgkmcnt(0)) before a barrier that precedes the stage issue.
//   vmcnt(6) before each tile-closing barrier => tile t+1's 8 loads landed.

typedef __attribute__((ext_vector_type(8))) short bf16x8;
typedef __attribute__((ext_vector_type(4))) float f32x4;

constexpr int cB = 4, cL = 2048, cD = 1280, cO = 2;
constexpr int NROW = cL * cO;          // 4096
constexpr int BM = 256, BN = 256, BK = 64;
constexpr int KT = cD / BK;            // 20 (even)
constexpr int MT2 = cL / BM;           // 8
constexpr int NT2 = NROW / BN;         // 16
constexpr int NBLK2 = cB * MT2 * NT2;  // 512

__device__ __forceinline__ unsigned short f2bf(float f) {
  unsigned int u = __float_as_uint(f);
  u += 0x7fffu + ((u >> 16) & 1u);
  return (unsigned short)(u >> 16);
}

#define GLOAD_LDS16(g, l)                                           \
  __builtin_amdgcn_global_load_lds(                                 \
      (const __attribute__((address_space(1))) void*)(g),           \
      (__attribute__((address_space(3))) void*)(l), 16, 0, 0)

// ---------------- pack: h -> bf16 A, (h*Wp) -> bf16 Beff ----------------
constexpr int ACH = cB * cL * cD / 8;
constexpr int BCH = cB * 2 * cL * cD / 8;

__global__ __launch_bounds__(256) void cph_pack(
    const float* __restrict__ h, const float* __restrict__ W,
    unsigned short* __restrict__ Apk, unsigned short* __restrict__ Bpk) {
  int idx = blockIdx.x * 256 + threadIdx.x;
  if (idx < ACH) {
    const float* src = h + (size_t)idx * 8;
    float4 x0 = *(const float4*)src;
    float4 x1 = *(const float4*)(src + 4);
    bf16x8 v;
    v[0] = (short)f2bf(x0.x); v[1] = (short)f2bf(x0.y);
    v[2] = (short)f2bf(x0.z); v[3] = (short)f2bf(x0.w);
    v[4] = (short)f2bf(x1.x); v[5] = (short)f2bf(x1.y);
    v[6] = (short)f2bf(x1.z); v[7] = (short)f2bf(x1.w);
    *(bf16x8*)(Apk + (size_t)idx * 8) = v;
  } else {
    idx -= ACH;
    if (idx >= BCH) return;
    int c = idx % (cD / 8);
    int n = (idx / (cD / 8)) % (2 * cL);
    int b = idx / ((cD / 8) * 2 * cL);
    int j = n >> 1, o = n & 1;
    const float* src = h + ((size_t)b * cL + j) * cD + c * 8;
    const float* ws  = W + (size_t)o * (2 * cD) + c * 8;
    float4 x0 = *(const float4*)src;
    float4 x1 = *(const float4*)(src + 4);
    float4 w0 = *(const float4*)ws;
    float4 w1 = *(const float4*)(ws + 4);
    bf16x8 v;
    v[0] = (short)f2bf(x0.x * w0.x); v[1] = (short)f2bf(x0.y * w0.y);
    v[2] = (short)f2bf(x0.z * w0.z); v[3] = (short)f2bf(x0.w * w0.w);
    v[4] = (short)f2bf(x1.x * w1.x); v[5] = (short)f2bf(x1.y * w1.y);
    v[6] = (short)f2bf(x1.z * w1.z); v[7] = (short)f2bf(x1.w * w1.w);
    *(bf16x8*)(Bpk + ((size_t)b * (2 * cL) + n) * cD + c * 8) = v;
  }
}

// ------------- GEMM: 256x256, 8 waves (2M x 4N), 4-phase/K-tile, vmcnt(6) -------------
__global__ __launch_bounds__(512, 2) void cph_gemm256(
    const unsigned short* __restrict__ Apk, const unsigned short* __restrict__ Bpk,
    const float* __restrict__ bias, float* __restrict__ out) {
  __shared__ __align__(16) char smem[131072];  // [2 buf][A 32K | B 32K]

  int bid = ((int)blockIdx.x & 7) * (NBLK2 / 8) + ((int)blockIdx.x >> 3);
  int b   = bid / (MT2 * NT2);
  int rem = bid % (MT2 * NT2);
  int mt  = rem / NT2, nt = rem % NT2;

  int tid  = threadIdx.x;
  int wave = tid >> 6, lane = tid & 63;
  int wm = wave >> 2, wn = wave & 3;   // per-wave C = 128 x 64

  const unsigned short* Ab = Apk + ((size_t)b * cL + mt * BM) * cD;
  const unsigned short* Bb = Bpk + ((size_t)b * NROW + nt * BN) * cD;

  int lr  = lane >> 3;                  // row within an 8-row slab
  int gc8 = ((lane & 7) ^ lr) * 8;      // inverse-swizzled global chunk offset

  // stage one 8-row A slab per wave (1 gload/wave): stripe s = block rows
  // [s*32,+32) (waves 0-3) u [128+s*32,+32) (waves 4-7).
  auto stageA = [&](int buf, int kt, int s) {
    int r0 = ((wave & 4) << 5) + s * 32 + (wave & 3) * 8;
    GLOAD_LDS16(Ab + (size_t)(r0 + lr) * cD + kt * BK + gc8,
                smem + buf * 65536 + r0 * 128);
  };
  // stage one 16-row B slab per wave (2 gloads/wave): half h = rows [h*128,+128)
  auto stageB = [&](int buf, int kt, int h) {
    int r0 = h * 128 + wave * 16;
    GLOAD_LDS16(Bb + (size_t)(r0 + lr) * cD + kt * BK + gc8,
                smem + buf * 65536 + 32768 + r0 * 128);
    GLOAD_LDS16(Bb + (size_t)(r0 + 8 + lr) * cD + kt * BK + gc8,
                smem + buf * 65536 + 32768 + (r0 + 8) * 128);
  };
  auto ldA = [&](int buf, int m, int kk) -> bf16x8 {
    int r  = wm * 128 + m * 16 + (lane & 15);
    int kc = kk * 4 + (lane >> 4);
    return *(const bf16x8*)(smem + buf * 65536 + r * 128 + (kc ^ (r & 7)) * 16);
  };
  auto ldB = [&](int buf, int nf, int kk) -> bf16x8 {
    int r  = wn * 64 + nf * 16 + (lane & 15);
    int kc = kk * 4 + (lane >> 4);
    return *(const bf16x8*)(smem + buf * 65536 + 32768 + r * 128 + (kc ^ (r & 7)) * 16);
  };

  f32x4 acc[8][4] = {};

  // prologue: tile0 complete (8 loads), tile1 partial (6: B + A stripes 0,1)
  stageB(0, 0, 0); stageB(0, 0, 1);
  stageA(0, 0, 0); stageA(0, 0, 1); stageA(0, 0, 2); stageA(0, 0, 3);
  stageB(1, 1, 0); stageB(1, 1, 1);
  stageA(1, 1, 0); stageA(1, 1, 1);
  asm volatile("s_waitcnt vmcnt(6)");          // tile 0 landed (no mem clobber!)
  __builtin_amdgcn_s_barrier();

  for (int tt = 0; tt < KT; tt += 2) {
    bool more = (tt + 2 < KT);
#pragma unroll
    for (int half = 0; half < 2; ++half) {   // tile t = tt+half in buf X = half
      int t = tt + half;
      const int X = half;
      bf16x8 bfr[4][2];
#pragma unroll
      for (int q = 0; q < 4; ++q) {
        // --- ds_read this phase's operands ---
        bf16x8 af[2][2];
#pragma unroll
        for (int mm = 0; mm < 2; ++mm)
#pragma unroll
          for (int kk = 0; kk < 2; ++kk)
            af[mm][kk] = ldA(X, 2 * q + mm, kk);
        if (q == 0) {
#pragma unroll
          for (int nf = 0; nf < 4; ++nf)
#pragma unroll
            for (int kk = 0; kk < 2; ++kk)
              bfr[nf][kk] = ldB(X, nf, kk);
        }
        // --- stage (<=2 gloads/wave/phase; regions freed per header proof) ---
        if (q == 0) {
          if (half == 0 || more) { stageA(X ^ 1, t + 1, 2); stageA(X ^ 1, t + 1, 3); }
        } else if (q == 1) {
          if (more) stageB(X, t + 2, 0);
        } else if (q == 2) {
          if (more) stageB(X, t + 2, 1);
        } else {
          if (more) { stageA(X, t + 2, 0); stageA(X, t + 2, 1); }
        }
        __builtin_amdgcn_s_barrier();
        asm volatile("s_waitcnt lgkmcnt(0)");     // reads complete before MFMA
        __builtin_amdgcn_sched_barrier(0);        // rule 18: pin MFMA below wait
        __builtin_amdgcn_s_setprio(1);
#pragma unroll
        for (int kk = 0; kk < 2; ++kk)
#pragma unroll
          for (int mm = 0; mm < 2; ++mm)
#pragma unroll
            for (int nf = 0; nf < 4; ++nf)
              acc[2 * q + mm][nf] = __builtin_amdgcn_mfma_f32_16x16x32_bf16(
                  af[mm][kk], bfr[nf][kk], acc[2 * q + mm][nf], 0, 0, 0);
        __builtin_amdgcn_s_setprio(0);
        if (q == 3) {
          if (more) asm volatile("s_waitcnt vmcnt(6)");   // tile t+1 landed
          else      asm volatile("s_waitcnt vmcnt(0)");   // tail drain
        }
        __builtin_amdgcn_s_barrier();
      }
    }
  }

  // epilogue: C/D 16x16 layout col = lane&15, row = (lane>>4)*4 + reg
  int i0 = mt * BM + wm * 128 + ((lane >> 4) << 2);
  int n0 = nt * BN + wn * 64 + (lane & 15);
  float badd = bias[n0 & 1];
  float* outb = out + (size_t)b * cL * NROW;
#pragma unroll
  for (int mf = 0; mf < 8; ++mf) {
#pragma unroll
    for (int r = 0; r < 4; ++r) {
      size_t rowoff = (size_t)(i0 + mf * 16 + r) * NROW;
#pragma unroll
      for (int nf = 0; nf < 4; ++nf)
        outb[rowoff + n0 + nf * 16] = acc[mf][nf][r] + badd;
    }
  }
}

// ---------------- fallback (ws too small): fused 128^2 full-grid GEMM ----------------
constexpr int fBM = 128, fBK = 64;
constexpr int fMT = cL / fBM, fNT = NROW / fBM;
constexpr int fNBLK = cB * fMT * fNT;

__global__ __launch_bounds__(256) void cph_gemm_fb(
    const float* __restrict__ h, const float* __restrict__ W,
    const float* __restrict__ bias, float* __restrict__ out) {
  __shared__ unsigned short Alds[fBM][fBK];
  __shared__ unsigned short Blds[fBM][fBK];
  int bid = ((int)blockIdx.x & 7) * (fNBLK / 8) + ((int)blockIdx.x >> 3);
  int b   = bid / (fMT * fNT);
  int rem = bid % (fMT * fNT);
  int mt  = rem / fNT, nt = rem % fNT;
  int tid = threadIdx.x, wave = tid >> 6, lane = tid & 63;
  int wm = wave >> 1, wn = wave & 1;
  f32x4 acc[4][4] = {};
  for (int kt = 0; kt < KT; ++kt) {
    __syncthreads();
#pragma unroll
    for (int it = 0; it < 4; ++it) {
      int chunk = tid + it * 256;
      int row = chunk >> 3, c = chunk & 7;
      int pc = c ^ (row & 7);
      const float* asrc = h + ((size_t)b * cL + mt * fBM + row) * cD + kt * fBK + c * 8;
      float4 a0 = *(const float4*)asrc;
      float4 a1 = *(const float4*)(asrc + 4);
      bf16x8 va;
      va[0] = (short)f2bf(a0.x); va[1] = (short)f2bf(a0.y);
      va[2] = (short)f2bf(a0.z); va[3] = (short)f2bf(a0.w);
      va[4] = (short)f2bf(a1.x); va[5] = (short)f2bf(a1.y);
      va[6] = (short)f2bf(a1.z); va[7] = (short)f2bf(a1.w);
      *(bf16x8*)&Alds[row][pc * 8] = va;
      int n = nt * fBM + row;
      int j = n >> 1, o = n & 1;
      const float* bsrc = h + ((size_t)b * cL + j) * cD + kt * fBK + c * 8;
      const float* wsrc = W + (size_t)o * (2 * cD) + kt * fBK + c * 8;
      float4 b0 = *(const float4*)bsrc;
      float4 b1 = *(const float4*)(bsrc + 4);
      float4 w0 = *(const float4*)wsrc;
      float4 w1 = *(const float4*)(wsrc + 4);
      bf16x8 vb;
      vb[0] = (short)f2bf(b0.x * w0.x); vb[1] = (short)f2bf(b0.y * w0.y);
      vb[2] = (short)f2bf(b0.z * w0.z); vb[3] = (short)f2bf(b0.w * w0.w);
      vb[4] = (short)f2bf(b1.x * w1.x); vb[5] = (short)f2bf(b1.y * w1.y);
      vb[6] = (short)f2bf(b1.z * w1.z); vb[7] = (short)f2bf(b1.w * w1.w);
      *(bf16x8*)&Blds[row][pc * 8] = vb;
    }
    __syncthreads();
#pragma unroll
    for (int kk = 0; kk < 2; ++kk) {
      int kc = kk * 4 + (lane >> 4);
      bf16x8 af[4], bfr[4];
#pragma unroll
      for (int m = 0; m < 4; ++m) {
        int r = wm * 64 + m * 16 + (lane & 15);
        af[m] = *(const bf16x8*)&Alds[r][(kc ^ (r & 7)) * 8];
      }
#pragma unroll
      for (int n = 0; n < 4; ++n) {
        int r = wn * 64 + n * 16 + (lane & 15);
        bfr[n] = *(const bf16x8*)&Blds[r][(kc ^ (r & 7)) * 8];
      }
#pragma unroll
      for (int m = 0; m < 4; ++m)
#pragma unroll
        for (int n = 0; n < 4; ++n)
          acc[m][n] = __builtin_amdgcn_mfma_f32_16x16x32_bf16(af[m], bfr[n], acc[m][n], 0, 0, 0);
    }
  }
  int i0 = mt * fBM + wm * 64 + ((lane >> 4) << 2);
  int n0 = nt * fBM + wn * 64 + (lane & 15);
  float badd = bias[n0 & 1];
  float* outb = out + (size_t)b * cL * NROW;
#pragma unroll
  for (int mf = 0; mf < 4; ++mf)
#pragma unroll
    for (int r = 0; r < 4; ++r) {
      size_t rowoff = (size_t)(i0 + mf * 16 + r) * NROW;
#pragma unroll
      for (int nf = 0; nf < 4; ++nf)
        outb[rowoff + n0 + nf * 16] = acc[mf][nf][r] + badd;
    }
}

extern "C" void kernel_launch(void* const* d_in, const int* in_sizes, int n_in,
                              void* d_out, int out_size, void* d_ws, size_t ws_size,
                              hipStream_t stream) {
  const float* h    = (const float*)d_in[0];
  const float* W    = (const float*)d_in[1];
  const float* bias = (const float*)d_in[2];
  float* out        = (float*)d_out;

  size_t a_elems = (size_t)cB * cL * cD;
  size_t b_elems = (size_t)cB * 2 * cL * cD;
  size_t need = (a_elems + b_elems) * sizeof(unsigned short);

  if (ws_size >= need) {
    unsigned short* Apk = (unsigned short*)d_ws;
    unsigned short* Bpk = Apk + a_elems;
    int total_chunks = ACH + BCH;
    cph_pack<<<(total_chunks + 255) / 256, 256, 0, stream>>>(h, W, Apk, Bpk);
    cph_gemm256<<<NBLK2, 512, 0, stream>>>(Apk, Bpk, bias, out);
  } else {
    cph_gemm_fb<<<fNBLK, 256, 0, stream>>>(h, W, bias, out);
  }
}

// Round 8
// 110.221 us; speedup vs baseline: 1.2274x; 1.0297x over previous
//
#include <hip/hip_runtime.h>
#include <hip/hip_bf16.h>

// ContactPredictionHead: logits[b,i,j,o] = sum_d h[b,i,d]*h[b,j,d]*Wp[o,d] + bias[o]
// (diff term antisymmetric -> cancels under symmetrization; prod term symmetric.)
// Batched GEMM: per batch  C[2048 x 4096] = A[2048 x 1280] * Beff^T,
//   Beff[2j+o, d] = h[b,j,d] * Wp[o,d],  row-major C == d_out layout.
// Round 8: LDS-pipe/MFMA-pipe CONCURRENCY. Rounds 5-7 all serialized the two
// pipes (reads -> barrier -> wait -> MFMA per phase => time = LDS + MFMA ~ 5850
// cyc/K-tile). New K-tile structure: NO intra-tile barriers; one entry barrier
// + one vmcnt(0) per tile (issue->wait distance = full tile >> HBM latency);
// inside, a 4-group register pipeline: reads for group g+1 are issued BEFORE
// group g's MFMA cluster (sched_barrier(0) pins the interleave; compiler emits
// counted lgkmcnt per its verified fine-grained behavior). Buffer proof:
// X^1's tile-(t-1) readers completed before t's entry barrier (lgkm FIFO
// precedes each wave's final MFMA of t-1); stage(t+1 -> X^1) issues after it;
// vmcnt(0)+barrier at t's end publishes X^1 to all waves for tile t+1.

typedef __attribute__((ext_vector_type(8))) short bf16x8;
typedef __attribute__((ext_vector_type(4))) float f32x4;

constexpr int cB = 4, cL = 2048, cD = 1280, cO = 2;
constexpr int NROW = cL * cO;          // 4096
constexpr int BM = 256, BN = 256, BK = 64;
constexpr int KT = cD / BK;            // 20
constexpr int MT2 = cL / BM;           // 8
constexpr int NT2 = NROW / BN;         // 16
constexpr int NBLK2 = cB * MT2 * NT2;  // 512

__device__ __forceinline__ unsigned short f2bf(float f) {
  unsigned int u = __float_as_uint(f);
  u += 0x7fffu + ((u >> 16) & 1u);
  return (unsigned short)(u >> 16);
}

#define GLOAD_LDS16(g, l)                                           \
  __builtin_amdgcn_global_load_lds(                                 \
      (const __attribute__((address_space(1))) void*)(g),           \
      (__attribute__((address_space(3))) void*)(l), 16, 0, 0)

// ---------------- pack: h -> bf16 A, (h*Wp) -> bf16 Beff ----------------
constexpr int ACH = cB * cL * cD / 8;
constexpr int BCH = cB * 2 * cL * cD / 8;

__global__ __launch_bounds__(256) void cph_pack(
    const float* __restrict__ h, const float* __restrict__ W,
    unsigned short* __restrict__ Apk, unsigned short* __restrict__ Bpk) {
  int idx = blockIdx.x * 256 + threadIdx.x;
  if (idx < ACH) {
    const float* src = h + (size_t)idx * 8;
    float4 x0 = *(const float4*)src;
    float4 x1 = *(const float4*)(src + 4);
    bf16x8 v;
    v[0] = (short)f2bf(x0.x); v[1] = (short)f2bf(x0.y);
    v[2] = (short)f2bf(x0.z); v[3] = (short)f2bf(x0.w);
    v[4] = (short)f2bf(x1.x); v[5] = (short)f2bf(x1.y);
    v[6] = (short)f2bf(x1.z); v[7] = (short)f2bf(x1.w);
    *(bf16x8*)(Apk + (size_t)idx * 8) = v;
  } else {
    idx -= ACH;
    if (idx >= BCH) return;
    int c = idx % (cD / 8);
    int n = (idx / (cD / 8)) % (2 * cL);
    int b = idx / ((cD / 8) * 2 * cL);
    int j = n >> 1, o = n & 1;
    const float* src = h + ((size_t)b * cL + j) * cD + c * 8;
    const float* ws  = W + (size_t)o * (2 * cD) + c * 8;
    float4 x0 = *(const float4*)src;
    float4 x1 = *(const float4*)(src + 4);
    float4 w0 = *(const float4*)ws;
    float4 w1 = *(const float4*)(ws + 4);
    bf16x8 v;
    v[0] = (short)f2bf(x0.x * w0.x); v[1] = (short)f2bf(x0.y * w0.y);
    v[2] = (short)f2bf(x0.z * w0.z); v[3] = (short)f2bf(x0.w * w0.w);
    v[4] = (short)f2bf(x1.x * w1.x); v[5] = (short)f2bf(x1.y * w1.y);
    v[6] = (short)f2bf(x1.z * w1.z); v[7] = (short)f2bf(x1.w * w1.w);
    *(bf16x8*)(Bpk + ((size_t)b * (2 * cL) + n) * cD + c * 8) = v;
  }
}

// ------------- GEMM: 256x256, 8 waves (2M x 4N), reg-pipelined tile, 1 barrier/tile -------------
__global__ __launch_bounds__(512, 2) void cph_gemm256(
    const unsigned short* __restrict__ Apk, const unsigned short* __restrict__ Bpk,
    const float* __restrict__ bias, float* __restrict__ out) {
  __shared__ __align__(16) char smem[131072];  // [2 buf][A 32K | B 32K]

  int bid = ((int)blockIdx.x & 7) * (NBLK2 / 8) + ((int)blockIdx.x >> 3);
  int b   = bid / (MT2 * NT2);
  int rem = bid % (MT2 * NT2);
  int mt  = rem / NT2, nt = rem % NT2;

  int tid  = threadIdx.x;
  int wave = tid >> 6, lane = tid & 63;
  int wm = wave >> 2, wn = wave & 3;   // per-wave C = 128 x 64

  const unsigned short* Ab = Apk + ((size_t)b * cL + mt * BM) * cD;
  const unsigned short* Bb = Bpk + ((size_t)b * NROW + nt * BN) * cD;

  int lr  = lane >> 3;                  // row within an 8-row slab
  int gc8 = ((lane & 7) ^ lr) * 8;      // inverse-swizzled global chunk offset

  auto stageA = [&](int buf, int kt, int s) {
    int r0 = ((wave & 4) << 5) + s * 32 + (wave & 3) * 8;
    GLOAD_LDS16(Ab + (size_t)(r0 + lr) * cD + kt * BK + gc8,
                smem + buf * 65536 + r0 * 128);
  };
  auto stageB = [&](int buf, int kt, int h) {
    int r0 = h * 128 + wave * 16;
    GLOAD_LDS16(Bb + (size_t)(r0 + lr) * cD + kt * BK + gc8,
                smem + buf * 65536 + 32768 + r0 * 128);
    GLOAD_LDS16(Bb + (size_t)(r0 + 8 + lr) * cD + kt * BK + gc8,
                smem + buf * 65536 + 32768 + (r0 + 8) * 128);
  };
  auto stageTile = [&](int kt, int buf) {   // 8 gloads/wave = full 64 KB tile
    stageB(buf, kt, 0); stageB(buf, kt, 1);
    stageA(buf, kt, 0); stageA(buf, kt, 1); stageA(buf, kt, 2); stageA(buf, kt, 3);
  };
  auto ldA = [&](int buf, int m, int kk) -> bf16x8 {
    int r  = wm * 128 + m * 16 + (lane & 15);
    int kc = kk * 4 + (lane >> 4);
    return *(const bf16x8*)(smem + buf * 65536 + r * 128 + (kc ^ (r & 7)) * 16);
  };
  auto ldB = [&](int buf, int nf, int kk) -> bf16x8 {
    int r  = wn * 64 + nf * 16 + (lane & 15);
    int kc = kk * 4 + (lane >> 4);
    return *(const bf16x8*)(smem + buf * 65536 + 32768 + r * 128 + (kc ^ (r & 7)) * 16);
  };

  f32x4 acc[8][4] = {};

#define MFMA16(base, A, B)                                                    \
  _Pragma("unroll")                                                           \
  for (int m_ = 0; m_ < 4; ++m_)                                              \
    _Pragma("unroll")                                                         \
    for (int nf_ = 0; nf_ < 4; ++nf_)                                         \
      acc[(base) + m_][nf_] = __builtin_amdgcn_mfma_f32_16x16x32_bf16(        \
          A[m_], B[nf_], acc[(base) + m_][nf_], 0, 0, 0);

  // prologue: stage tile 0, drain, publish
  stageTile(0, 0);
  asm volatile("s_waitcnt vmcnt(0)");
  __builtin_amdgcn_s_barrier();

  for (int t = 0; t < KT; ++t) {
    const int X = t & 1;
    // issue next tile's DMA first: lands while this tile computes
    if (t + 1 < KT) stageTile(t + 1, X ^ 1);

    bf16x8 B0[4], B1[4], Ae[4], Ao[4];
    // group (h0,k0) operands + B(k0)
#pragma unroll
    for (int nf = 0; nf < 4; ++nf) B0[nf] = ldB(X, nf, 0);
#pragma unroll
    for (int m = 0; m < 4; ++m) Ae[m] = ldA(X, m, 0);

    // reads for (h1,k0), then MFMA (h0,k0)
#pragma unroll
    for (int m = 0; m < 4; ++m) Ao[m] = ldA(X, m + 4, 0);
    __builtin_amdgcn_sched_barrier(0);
    __builtin_amdgcn_s_setprio(1);
    MFMA16(0, Ae, B0);
    __builtin_amdgcn_s_setprio(0);

    // reads for (h0,k1) + B(k1), then MFMA (h1,k0)
#pragma unroll
    for (int nf = 0; nf < 4; ++nf) B1[nf] = ldB(X, nf, 1);
#pragma unroll
    for (int m = 0; m < 4; ++m) Ae[m] = ldA(X, m, 1);
    __builtin_amdgcn_sched_barrier(0);
    __builtin_amdgcn_s_setprio(1);
    MFMA16(4, Ao, B0);
    __builtin_amdgcn_s_setprio(0);

    // reads for (h1,k1), then MFMA (h0,k1)
#pragma unroll
    for (int m = 0; m < 4; ++m) Ao[m] = ldA(X, m + 4, 1);
    __builtin_amdgcn_sched_barrier(0);
    __builtin_amdgcn_s_setprio(1);
    MFMA16(0, Ae, B1);
    __builtin_amdgcn_s_setprio(0);

    // MFMA (h1,k1)
    __builtin_amdgcn_sched_barrier(0);
    __builtin_amdgcn_s_setprio(1);
    MFMA16(4, Ao, B1);
    __builtin_amdgcn_s_setprio(0);

    if (t + 1 < KT) {
      // t+1's 8 gloads were issued a full tile ago (~2500+ cyc >> HBM 900)
      asm volatile("s_waitcnt vmcnt(0)");
      __builtin_amdgcn_s_barrier();
    }
  }
#undef MFMA16

  // epilogue: C/D 16x16 layout col = lane&15, row = (lane>>4)*4 + reg
  int i0 = mt * BM + wm * 128 + ((lane >> 4) << 2);
  int n0 = nt * BN + wn * 64 + (lane & 15);
  float badd = bias[n0 & 1];
  float* outb = out + (size_t)b * cL * NROW;
#pragma unroll
  for (int mf = 0; mf < 8; ++mf) {
#pragma unroll
    for (int r = 0; r < 4; ++r) {
      size_t rowoff = (size_t)(i0 + mf * 16 + r) * NROW;
#pragma unroll
      for (int nf = 0; nf < 4; ++nf)
        outb[rowoff + n0 + nf * 16] = acc[mf][nf][r] + badd;
    }
  }
}

// ---------------- fallback (ws too small): fused 128^2 full-grid GEMM ----------------
constexpr int fBM = 128, fBK = 64;
constexpr int fMT = cL / fBM, fNT = NROW / fBM;
constexpr int fNBLK = cB * fMT * fNT;

__global__ __launch_bounds__(256) void cph_gemm_fb(
    const float* __restrict__ h, const float* __restrict__ W,
    const float* __restrict__ bias, float* __restrict__ out) {
  __shared__ unsigned short Alds[fBM][fBK];
  __shared__ unsigned short Blds[fBM][fBK];
  int bid = ((int)blockIdx.x & 7) * (fNBLK / 8) + ((int)blockIdx.x >> 3);
  int b   = bid / (fMT * fNT);
  int rem = bid % (fMT * fNT);
  int mt  = rem / fNT, nt = rem % fNT;
  int tid = threadIdx.x, wave = tid >> 6, lane = tid & 63;
  int wm = wave >> 1, wn = wave & 1;
  f32x4 acc[4][4] = {};
  for (int kt = 0; kt < KT; ++kt) {
    __syncthreads();
#pragma unroll
    for (int it = 0; it < 4; ++it) {
      int chunk = tid + it * 256;
      int row = chunk >> 3, c = chunk & 7;
      int pc = c ^ (row & 7);
      const float* asrc = h + ((size_t)b * cL + mt * fBM + row) * cD + kt * fBK + c * 8;
      float4 a0 = *(const float4*)asrc;
      float4 a1 = *(const float4*)(asrc + 4);
      bf16x8 va;
      va[0] = (short)f2bf(a0.x); va[1] = (short)f2bf(a0.y);
      va[2] = (short)f2bf(a0.z); va[3] = (short)f2bf(a0.w);
      va[4] = (short)f2bf(a1.x); va[5] = (short)f2bf(a1.y);
      va[6] = (short)f2bf(a1.z); va[7] = (short)f2bf(a1.w);
      *(bf16x8*)&Alds[row][pc * 8] = va;
      int n = nt * fBM + row;
      int j = n >> 1, o = n & 1;
      const float* bsrc = h + ((size_t)b * cL + j) * cD + kt * fBK + c * 8;
      const float* wsrc = W + (size_t)o * (2 * cD) + kt * fBK + c * 8;
      float4 b0 = *(const float4*)bsrc;
      float4 b1 = *(const float4*)(bsrc + 4);
      float4 w0 = *(const float4*)wsrc;
      float4 w1 = *(const float4*)(wsrc + 4);
      bf16x8 vb;
      vb[0] = (short)f2bf(b0.x * w0.x); vb[1] = (short)f2bf(b0.y * w0.y);
      vb[2] = (short)f2bf(b0.z * w0.z); vb[3] = (short)f2bf(b0.w * w0.w);
      vb[4] = (short)f2bf(b1.x * w1.x); vb[5] = (short)f2bf(b1.y * w1.y);
      vb[6] = (short)f2bf(b1.z * w1.z); vb[7] = (short)f2bf(b1.w * w1.w);
      *(bf16x8*)&Blds[row][pc * 8] = vb;
    }
    __syncthreads();
#pragma unroll
    for (int kk = 0; kk < 2; ++kk) {
      int kc = kk * 4 + (lane >> 4);
      bf16x8 af[4], bfr[4];
#pragma unroll
      for (int m = 0; m < 4; ++m) {
        int r = wm * 64 + m * 16 + (lane & 15);
        af[m] = *(const bf16x8*)&Alds[r][(kc ^ (r & 7)) * 8];
      }
#pragma unroll
      for (int n = 0; n < 4; ++n) {
        int r = wn * 64 + n * 16 + (lane & 15);
        bfr[n] = *(const bf16x8*)&Blds[r][(kc ^ (r & 7)) * 8];
      }
#pragma unroll
      for (int m = 0; m < 4; ++m)
#pragma unroll
        for (int n = 0; n < 4; ++n)
          acc[m][n] = __builtin_amdgcn_mfma_f32_16x16x32_bf16(af[m], bfr[n], acc[m][n], 0, 0, 0);
    }
  }
  int i0 = mt * fBM + wm * 64 + ((lane >> 4) << 2);
  int n0 = nt * fBM + wn * 64 + (lane & 15);
  float badd = bias[n0 & 1];
  float* outb = out + (size_t)b * cL * NROW;
#pragma unroll
  for (int mf = 0; mf < 4; ++mf)
#pragma unroll
    for (int r = 0; r < 4; ++r) {
      size_t rowoff = (size_t)(i0 + mf * 16 + r) * NROW;
#pragma unroll
      for (int nf = 0; nf < 4; ++nf)
        outb[rowoff + n0 + nf * 16] = acc[mf][nf][r] + badd;
    }
}

extern "C" void kernel_launch(void* const* d_in, const int* in_sizes, int n_in,
                              void* d_out, int out_size, void* d_ws, size_t ws_size,
                              hipStream_t stream) {
  const float* h    = (const float*)d_in[0];
  const float* W    = (const float*)d_in[1];
  const float* bias = (const float*)d_in[2];
  float* out        = (float*)d_out;

  size_t a_elems = (size_t)cB * cL * cD;
  size_t b_elems = (size_t)cB * 2 * cL * cD;
  size_t need = (a_elems + b_elems) * sizeof(unsigned short);

  if (ws_size >= need) {
    unsigned short* Apk = (unsigned short*)d_ws;
    unsigned short* Bpk = Apk + a_elems;
    int total_chunks = ACH + BCH;
    cph_pack<<<(total_chunks + 255) / 256, 256, 0, stream>>>(h, W, Apk, Bpk);
    cph_gemm256<<<NBLK2, 512, 0, stream>>>(Apk, Bpk, bias, out);
  } else {
    cph_gemm_fb<<<fNBLK, 256, 0, stream>>>(h, W, bias, out);
  }
}

// Round 9
// 109.408 us; speedup vs baseline: 1.2365x; 1.0074x over previous
//
#include <hip/hip_runtime.h>
#include <hip/hip_bf16.h>

// ContactPredictionHead: logits[b,i,j,o] = sum_d h[b,i,d]*h[b,j,d]*Wp[o,d] + bias[o]
// (diff term antisymmetric -> cancels under symmetrization; prod term symmetric.)
// Batched GEMM: per batch  C[2048 x 4096] = A[2048 x 1280] * Beff^T,
//   Beff[2j+o, d] = h[b,j,d] * Wp[o,d],  row-major C == d_out layout.
// Round 9: (a) NO sched_barrier pins -- C++ ds loads carry their own deps, so
// the compiler interleaves read-issue among MFMAs with counted lgkmcnt (its
// verified behavior); (b) persistent 256-block grid, 2 output tiles per block
// (orig, orig+256 -> mostly same B-panel -> L2 reuse); part-1 tile-0 staged at
// part-0's last K-tile so its latency hides under part-0's epilogue stores;
// (c) R8's race-free frame kept: 1 vmcnt(0) + 1 barrier per K-tile; at each
// barrier all reads of the outgoing buffer have COMPLETED (lgkm in-order
// precedes the MFMAs that consumed them), so restaging after it is safe.

typedef __attribute__((ext_vector_type(8))) short bf16x8;
typedef __attribute__((ext_vector_type(4))) float f32x4;

constexpr int cB = 4, cL = 2048, cD = 1280, cO = 2;
constexpr int NROW = cL * cO;          // 4096
constexpr int BM = 256, BN = 256, BK = 64;
constexpr int KT = cD / BK;            // 20
constexpr int MT2 = cL / BM;           // 8
constexpr int NT2 = NROW / BN;         // 16
constexpr int NTILE = cB * MT2 * NT2;  // 512 output tiles
constexpr int NPBLK = NTILE / 2;       // 256 persistent blocks

__device__ __forceinline__ unsigned short f2bf(float f) {
  unsigned int u = __float_as_uint(f);
  u += 0x7fffu + ((u >> 16) & 1u);
  return (unsigned short)(u >> 16);
}

#define GLOAD_LDS16(g, l)                                           \
  __builtin_amdgcn_global_load_lds(                                 \
      (const __attribute__((address_space(1))) void*)(g),           \
      (__attribute__((address_space(3))) void*)(l), 16, 0, 0)

// ---------------- pack: h -> bf16 A, (h*Wp) -> bf16 Beff ----------------
constexpr int ACH = cB * cL * cD / 8;
constexpr int BCH = cB * 2 * cL * cD / 8;

__global__ __launch_bounds__(256) void cph_pack(
    const float* __restrict__ h, const float* __restrict__ W,
    unsigned short* __restrict__ Apk, unsigned short* __restrict__ Bpk) {
  int idx = blockIdx.x * 256 + threadIdx.x;
  if (idx < ACH) {
    const float* src = h + (size_t)idx * 8;
    float4 x0 = *(const float4*)src;
    float4 x1 = *(const float4*)(src + 4);
    bf16x8 v;
    v[0] = (short)f2bf(x0.x); v[1] = (short)f2bf(x0.y);
    v[2] = (short)f2bf(x0.z); v[3] = (short)f2bf(x0.w);
    v[4] = (short)f2bf(x1.x); v[5] = (short)f2bf(x1.y);
    v[6] = (short)f2bf(x1.z); v[7] = (short)f2bf(x1.w);
    *(bf16x8*)(Apk + (size_t)idx * 8) = v;
  } else {
    idx -= ACH;
    if (idx >= BCH) return;
    int c = idx % (cD / 8);
    int n = (idx / (cD / 8)) % (2 * cL);
    int b = idx / ((cD / 8) * 2 * cL);
    int j = n >> 1, o = n & 1;
    const float* src = h + ((size_t)b * cL + j) * cD + c * 8;
    const float* ws  = W + (size_t)o * (2 * cD) + c * 8;
    float4 x0 = *(const float4*)src;
    float4 x1 = *(const float4*)(src + 4);
    float4 w0 = *(const float4*)ws;
    float4 w1 = *(const float4*)(ws + 4);
    bf16x8 v;
    v[0] = (short)f2bf(x0.x * w0.x); v[1] = (short)f2bf(x0.y * w0.y);
    v[2] = (short)f2bf(x0.z * w0.z); v[3] = (short)f2bf(x0.w * w0.w);
    v[4] = (short)f2bf(x1.x * w1.x); v[5] = (short)f2bf(x1.y * w1.y);
    v[6] = (short)f2bf(x1.z * w1.z); v[7] = (short)f2bf(x1.w * w1.w);
    *(bf16x8*)(Bpk + ((size_t)b * (2 * cL) + n) * cD + c * 8) = v;
  }
}

// ------------- GEMM: 256x256, 8 waves (2M x 4N), 2 tiles/block, reg-pipelined -------------
__global__ __launch_bounds__(512, 2) void cph_gemm256(
    const unsigned short* __restrict__ Apk, const unsigned short* __restrict__ Bpk,
    const float* __restrict__ bias, float* __restrict__ out) {
  __shared__ __align__(16) char smem[131072];  // [2 buf][A 32K | B 32K]

  int tid  = threadIdx.x;
  int wave = tid >> 6, lane = tid & 63;
  int wm = wave >> 2, wn = wave & 3;   // per-wave C = 128 x 64

  // decode both output tiles of this persistent block
  int bv[2], mtv[2], ntv[2];
  const unsigned short *Abv[2], *Bbv[2];
#pragma unroll
  for (int p = 0; p < 2; ++p) {
    int orig = (int)blockIdx.x + p * NPBLK;
    int bid  = (orig & 7) * (NTILE / 8) + (orig >> 3);   // bijective XCD swizzle
    bv[p]  = bid / (MT2 * NT2);
    int rem = bid % (MT2 * NT2);
    mtv[p] = rem / NT2;
    ntv[p] = rem % NT2;
    Abv[p] = Apk + ((size_t)bv[p] * cL + mtv[p] * BM) * cD;
    Bbv[p] = Bpk + ((size_t)bv[p] * NROW + ntv[p] * BN) * cD;
  }

  int lr  = lane >> 3;                  // row within an 8-row slab
  int gc8 = ((lane & 7) ^ lr) * 8;      // inverse-swizzled global chunk offset

  auto stageA = [&](const unsigned short* Ab, int buf, int kt, int s) {
    int r0 = ((wave & 4) << 5) + s * 32 + (wave & 3) * 8;
    GLOAD_LDS16(Ab + (size_t)(r0 + lr) * cD + kt * BK + gc8,
                smem + buf * 65536 + r0 * 128);
  };
  auto stageB = [&](const unsigned short* Bb, int buf, int kt, int h) {
    int r0 = h * 128 + wave * 16;
    GLOAD_LDS16(Bb + (size_t)(r0 + lr) * cD + kt * BK + gc8,
                smem + buf * 65536 + 32768 + r0 * 128);
    GLOAD_LDS16(Bb + (size_t)(r0 + 8 + lr) * cD + kt * BK + gc8,
                smem + buf * 65536 + 32768 + (r0 + 8) * 128);
  };
  auto stageTile = [&](const unsigned short* Ab, const unsigned short* Bb,
                       int kt, int buf) {   // 8 gloads/thread = full 64 KB tile
    stageB(Bb, buf, kt, 0); stageB(Bb, buf, kt, 1);
    stageA(Ab, buf, kt, 0); stageA(Ab, buf, kt, 1);
    stageA(Ab, buf, kt, 2); stageA(Ab, buf, kt, 3);
  };
  auto ldA = [&](int buf, int m, int kk) -> bf16x8 {
    int r  = wm * 128 + m * 16 + (lane & 15);
    int kc = kk * 4 + (lane >> 4);
    return *(const bf16x8*)(smem + buf * 65536 + r * 128 + (kc ^ (r & 7)) * 16);
  };
  auto ldB = [&](int buf, int nf, int kk) -> bf16x8 {
    int r  = wn * 64 + nf * 16 + (lane & 15);
    int kc = kk * 4 + (lane >> 4);
    return *(const bf16x8*)(smem + buf * 65536 + 32768 + r * 128 + (kc ^ (r & 7)) * 16);
  };

  f32x4 acc[8][4];

#define MFMA16(base, A, B)                                                    \
  _Pragma("unroll")                                                           \
  for (int m_ = 0; m_ < 4; ++m_)                                              \
    _Pragma("unroll")                                                         \
    for (int nf_ = 0; nf_ < 4; ++nf_)                                         \
      acc[(base) + m_][nf_] = __builtin_amdgcn_mfma_f32_16x16x32_bf16(        \
          A[m_], B[nf_], acc[(base) + m_][nf_], 0, 0, 0);

  // prologue: stage part-0 tile 0
  stageTile(Abv[0], Bbv[0], 0, 0);

  for (int part = 0; part < 2; ++part) {
    const unsigned short* Ap = Abv[part];
    const unsigned short* Bp = Bbv[part];
    // publish this part's tile 0 (part 1: loads were issued before part-0's
    // epilogue stores; vmcnt(0) also drains those stores -- acceptable)
    asm volatile("s_waitcnt vmcnt(0)");
    __builtin_amdgcn_s_barrier();

#pragma unroll
    for (int mf = 0; mf < 8; ++mf)
#pragma unroll
      for (int nf = 0; nf < 4; ++nf)
        acc[mf][nf] = (f32x4){0.f, 0.f, 0.f, 0.f};

    for (int t = 0; t < KT; ++t) {
      const int X = t & 1;
      // issue next tile's DMA first: lands while this tile computes
      if (t + 1 < KT)      stageTile(Ap, Bp, t + 1, X ^ 1);
      else if (part == 0)  stageTile(Abv[1], Bbv[1], 0, X ^ 1);  // part-1 tile 0 -> buf 0

      bf16x8 B0[4], B1[4], Ae[4], Ao[4];
#pragma unroll
      for (int nf = 0; nf < 4; ++nf) B0[nf] = ldB(X, nf, 0);
#pragma unroll
      for (int m = 0; m < 4; ++m) Ae[m] = ldA(X, m, 0);
#pragma unroll
      for (int m = 0; m < 4; ++m) Ao[m] = ldA(X, m + 4, 0);
      __builtin_amdgcn_s_setprio(1);
      MFMA16(0, Ae, B0);
      __builtin_amdgcn_s_setprio(0);

#pragma unroll
      for (int nf = 0; nf < 4; ++nf) B1[nf] = ldB(X, nf, 1);
#pragma unroll
      for (int m = 0; m < 4; ++m) Ae[m] = ldA(X, m, 1);
      __builtin_amdgcn_s_setprio(1);
      MFMA16(4, Ao, B0);
      __builtin_amdgcn_s_setprio(0);

#pragma unroll
      for (int m = 0; m < 4; ++m) Ao[m] = ldA(X, m + 4, 1);
      __builtin_amdgcn_s_setprio(1);
      MFMA16(0, Ae, B1);
      __builtin_amdgcn_s_setprio(0);

      __builtin_amdgcn_s_setprio(1);
      MFMA16(4, Ao, B1);
      __builtin_amdgcn_s_setprio(0);

      if (t + 1 < KT) {
        asm volatile("s_waitcnt vmcnt(0)");   // next tile landed (issued ~full tile ago)
        __builtin_amdgcn_s_barrier();
      }
    }

    // epilogue: C/D 16x16 layout col = lane&15, row = (lane>>4)*4 + reg
    int i0 = mtv[part] * BM + wm * 128 + ((lane >> 4) << 2);
    int n0 = ntv[part] * BN + wn * 64 + (lane & 15);
    float badd = bias[n0 & 1];
    float* outb = out + (size_t)bv[part] * cL * NROW;
#pragma unroll
    for (int mf = 0; mf < 8; ++mf) {
#pragma unroll
      for (int r = 0; r < 4; ++r) {
        size_t rowoff = (size_t)(i0 + mf * 16 + r) * NROW;
#pragma unroll
        for (int nf = 0; nf < 4; ++nf)
          outb[rowoff + n0 + nf * 16] = acc[mf][nf][r] + badd;
      }
    }
  }
#undef MFMA16
}

// ---------------- fallback (ws too small): fused 128^2 full-grid GEMM ----------------
constexpr int fBM = 128, fBK = 64;
constexpr int fMT = cL / fBM, fNT = NROW / fBM;
constexpr int fNBLK = cB * fMT * fNT;

__global__ __launch_bounds__(256) void cph_gemm_fb(
    const float* __restrict__ h, const float* __restrict__ W,
    const float* __restrict__ bias, float* __restrict__ out) {
  __shared__ unsigned short Alds[fBM][fBK];
  __shared__ unsigned short Blds[fBM][fBK];
  int bid = ((int)blockIdx.x & 7) * (fNBLK / 8) + ((int)blockIdx.x >> 3);
  int b   = bid / (fMT * fNT);
  int rem = bid % (fMT * fNT);
  int mt  = rem / fNT, nt = rem % fNT;
  int tid = threadIdx.x, wave = tid >> 6, lane = tid & 63;
  int wm = wave >> 1, wn = wave & 1;
  f32x4 acc[4][4] = {};
  for (int kt = 0; kt < KT; ++kt) {
    __syncthreads();
#pragma unroll
    for (int it = 0; it < 4; ++it) {
      int chunk = tid + it * 256;
      int row = chunk >> 3, c = chunk & 7;
      int pc = c ^ (row & 7);
      const float* asrc = h + ((size_t)b * cL + mt * fBM + row) * cD + kt * fBK + c * 8;
      float4 a0 = *(const float4*)asrc;
      float4 a1 = *(const float4*)(asrc + 4);
      bf16x8 va;
      va[0] = (short)f2bf(a0.x); va[1] = (short)f2bf(a0.y);
      va[2] = (short)f2bf(a0.z); va[3] = (short)f2bf(a0.w);
      va[4] = (short)f2bf(a1.x); va[5] = (short)f2bf(a1.y);
      va[6] = (short)f2bf(a1.z); va[7] = (short)f2bf(a1.w);
      *(bf16x8*)&Alds[row][pc * 8] = va;
      int n = nt * fBM + row;
      int j = n >> 1, o = n & 1;
      const float* bsrc = h + ((size_t)b * cL + j) * cD + kt * fBK + c * 8;
      const float* wsrc = W + (size_t)o * (2 * cD) + kt * fBK + c * 8;
      float4 b0 = *(const float4*)bsrc;
      float4 b1 = *(const float4*)(bsrc + 4);
      float4 w0 = *(const float4*)wsrc;
      float4 w1 = *(const float4*)(wsrc + 4);
      bf16x8 vb;
      vb[0] = (short)f2bf(b0.x * w0.x); vb[1] = (short)f2bf(b0.y * w0.y);
      vb[2] = (short)f2bf(b0.z * w0.z); vb[3] = (short)f2bf(b0.w * w0.w);
      vb[4] = (short)f2bf(b1.x * w1.x); vb[5] = (short)f2bf(b1.y * w1.y);
      vb[6] = (short)f2bf(b1.z * w1.z); vb[7] = (short)f2bf(b1.w * w1.w);
      *(bf16x8*)&Blds[row][pc * 8] = vb;
    }
    __syncthreads();
#pragma unroll
    for (int kk = 0; kk < 2; ++kk) {
      int kc = kk * 4 + (lane >> 4);
      bf16x8 af[4], bfr[4];
#pragma unroll
      for (int m = 0; m < 4; ++m) {
        int r = wm * 64 + m * 16 + (lane & 15);
        af[m] = *(const bf16x8*)&Alds[r][(kc ^ (r & 7)) * 8];
      }
#pragma unroll
      for (int n = 0; n < 4; ++n) {
        int r = wn * 64 + n * 16 + (lane & 15);
        bfr[n] = *(const bf16x8*)&Blds[r][(kc ^ (r & 7)) * 8];
      }
#pragma unroll
      for (int m = 0; m < 4; ++m)
#pragma unroll
        for (int n = 0; n < 4; ++n)
          acc[m][n] = __builtin_amdgcn_mfma_f32_16x16x32_bf16(af[m], bfr[n], acc[m][n], 0, 0, 0);
    }
  }
  int i0 = mt * fBM + wm * 64 + ((lane >> 4) << 2);
  int n0 = nt * fBM + wn * 64 + (lane & 15);
  float badd = bias[n0 & 1];
  float* outb = out + (size_t)b * cL * NROW;
#pragma unroll
  for (int mf = 0; mf < 4; ++mf)
#pragma unroll
    for (int r = 0; r < 4; ++r) {
      size_t rowoff = (size_t)(i0 + mf * 16 + r) * NROW;
#pragma unroll
      for (int nf = 0; nf < 4; ++nf)
        outb[rowoff + n0 + nf * 16] = acc[mf][nf][r] + badd;
    }
}

extern "C" void kernel_launch(void* const* d_in, const int* in_sizes, int n_in,
                              void* d_out, int out_size, void* d_ws, size_t ws_size,
                              hipStream_t stream) {
  const float* h    = (const float*)d_in[0];
  const float* W    = (const float*)d_in[1];
  const float* bias = (const float*)d_in[2];
  float* out        = (float*)d_out;

  size_t a_elems = (size_t)cB * cL * cD;
  size_t b_elems = (size_t)cB * 2 * cL * cD;
  size_t need = (a_elems + b_elems) * sizeof(unsigned short);

  if (ws_size >= need) {
    unsigned short* Apk = (unsigned short*)d_ws;
    unsigned short* Bpk = Apk + a_elems;
    int total_chunks = ACH + BCH;
    cph_pack<<<(total_chunks + 255) / 256, 256, 0, stream>>>(h, W, Apk, Bpk);
    cph_gemm256<<<NPBLK, 512, 0, stream>>>(Apk, Bpk, bias, out);
  } else {
    cph_gemm_fb<<<fNBLK, 256, 0, stream>>>(h, W, bias, out);
  }
}